// Round 14
// baseline (29853.098 us; speedup 1.0000x reference)
//
#include <hip/hip_runtime.h>
#include <stdint.h>
#include <math.h>

#define NS 8192
#define NSTEPS 200
#define DBc 128

typedef unsigned int u32;
typedef unsigned short u16;

// ws float-offset layout (float slots), total ~29.5 MB
#define WS_KEYINIT 64      // u32[2]
#define WS_KFIN   66       // u32[2]
#define WS_KC     128      // u32[400]
#define WS_KST    640      // u32[6*199] -> ends 1834
#define WS_IDX    2048     // int[200]
#define WS_LL     4096                    // [200][8192] -> ends 1642496
#define WS_H      (WS_LL+NSTEPS*NS)       // -> ends 3280896
#define WS_LLN    (WS_H+NSTEPS*NS)        // -> ends 4919296
#define WS_ANC_F  (WS_LLN+NSTEPS*NS)      // u16[199*8192] = 815104 slots -> ends 5734400
#define WS_CKPT   (WS_ANC_F+(NSTEPS-1)*NS/2)  // [25][8192][8] -> ends 7372800

// ======================= threefry2x32-20 (validated r1-r12) =======================
__device__ __forceinline__ u32 rotl32(u32 v, int r){ return (v<<r)|(v>>(32-r)); }

__device__ __forceinline__ void tf2x32(u32 k0,u32 k1,u32 c0,u32 c1,u32&o0,u32&o1){
  u32 ks2 = k0^k1^0x1BD11BDAu;
  u32 x0=c0+k0, x1=c1+k1;
#define TFR(R) { x0+=x1; x1=rotl32(x1,(R)); x1^=x0; }
  TFR(13) TFR(15) TFR(26) TFR(6)
  x0+=k1;  x1+=ks2+1u;
  TFR(17) TFR(29) TFR(16) TFR(24)
  x0+=ks2; x1+=k0+2u;
  TFR(13) TFR(15) TFR(26) TFR(6)
  x0+=k0;  x1+=k1+3u;
  TFR(17) TFR(29) TFR(16) TFR(24)
  x0+=k1;  x1+=ks2+4u;
  TFR(13) TFR(15) TFR(26) TFR(6)
  x0+=ks2; x1+=k0+5u;
#undef TFR
  o0=x0; o1=x1;
}

__device__ __forceinline__ u32 jax_bits_elem(u32 k0,u32 k1,u32 i){
  u32 a,b; tf2x32(k0,k1,0u,i,a,b); return a^b;
}

__device__ __forceinline__ float bits_to_f01(u32 bits){
  return __uint_as_float((bits>>9)|0x3f800000u) - 1.0f;
}

__device__ __forceinline__ float log1pf_acc(float a){
#pragma clang fp contract(off)
  float u = 1.0f + a;
  if (u == 1.0f) return a;
  float l = logf(u);
  return l * (a / (u - 1.0f));
}

__device__ __forceinline__ float erfinv_xla(float x){
#pragma clang fp contract(off)
  float a = -(x*x);
  float w = -log1pf_acc(a);
  float p;
  if (w < 5.0f){
    w = w - 2.5f;
    p = 2.81022636e-08f;
    p = 3.43273939e-07f + p*w;
    p = -3.5233877e-06f + p*w;
    p = -4.39150654e-06f + p*w;
    p = 0.00021858087f  + p*w;
    p = -0.00125372503f + p*w;
    p = -0.00417768164f + p*w;
    p = 0.246640727f    + p*w;
    p = 1.50140941f     + p*w;
  } else {
    w = sqrtf(w) - 3.0f;
    p = -0.000200214257f;
    p = 0.000100950558f + p*w;
    p = 0.00134934322f  + p*w;
    p = -0.00367342844f + p*w;
    p = 0.00573950773f  + p*w;
    p = -0.0076224613f  + p*w;
    p = 0.00943887047f  + p*w;
    p = 1.00167406f     + p*w;
    p = 2.83297682f     + p*w;
  }
  return p*x;
}

__device__ __forceinline__ float jax_normal_elem(u32 k0,u32 k1,u32 i){
#pragma clang fp contract(off)
  float f = bits_to_f01(jax_bits_elem(k0,k1,i));
  float u = f*2.0f + (-0.99999994039535522f);
  u = fmaxf(-0.99999994039535522f, u);
  return 1.41421356237309515f * erfinv_xla(u);
}

__device__ __forceinline__ float jax_uniform01_scalar(u32 k0,u32 k1){
  return bits_to_f01(jax_bits_elem(k0,k1,0u));
}

// ======================= wave helpers =======================
__device__ __forceinline__ float wave_max(float v){
  #pragma unroll
  for(int m=1;m<64;m<<=1) v=fmaxf(v,__shfl_xor(v,m,64));
  return v;
}
__device__ __forceinline__ float wave_incl_scan(float v,int lane){
  #pragma unroll
  for(int o=1;o<64;o<<=1){ float u=__shfl_up(v,o,64); if(lane>=o) v+=u; }
  return v;
}

__device__ void chol8(const float* A,float* L){
  for(int c=0;c<8;c++){
    for(int r=c;r<8;r++){
      float s=A[r*8+c];
      for(int k=0;k<c;k++) s-=L[r*(r+1)/2+k]*L[c*(c+1)/2+k];
      L[r*(r+1)/2+c]=(r==c)? sqrtf(s) : s/L[c*(c+1)/2+c];
    }
  }
}

// ======================= k_pre: key chain (validated r5-r12) =======================
__global__ __launch_bounds__(256) void k_pre(const int* __restrict__ seedp, float* wsf){
  u32* KI=(u32*)(wsf+WS_KEYINIT); u32* KF=(u32*)(wsf+WS_KFIN);
  u32* KC=(u32*)(wsf+WS_KC); u32* KST=(u32*)(wsf+WS_KST);
  int tid=threadIdx.x;
  if(tid==0){
    u32 s=(u32)seedp[0];
    u32 a,b;
    tf2x32(0u,s,0u,0u,a,b); KC[0]=a; KC[1]=b;      // key_0 = split(key).child0
    tf2x32(0u,s,0u,1u,a,b); KI[0]=a; KI[1]=b;      // key_init = child1
    for(int t=1;t<NSTEPS;t++){
      tf2x32(KC[2*(t-1)],KC[2*(t-1)+1],0u,0u,a,b);
      KC[2*t]=a; KC[2*t+1]=b;
    }
    KF[0]=KC[2*(NSTEPS-1)]; KF[1]=KC[2*(NSTEPS-1)+1];
  }
  __syncthreads();
  int t=tid;
  if(t>=1 && t<NSTEPS){
    u32 k0=KC[2*(t-1)], k1=KC[2*(t-1)+1];
    u32 s0,s1; tf2x32(k0,k1,0u,1u,s0,s1);          // key_step
    u32 ka0,ka1; tf2x32(s0,s1,0u,1u,ka0,ka1);      // k_anc
    u32 t0,t1;  tf2x32(s0,s1,0u,0u,t0,t1);
    u32 kr0,kr1; tf2x32(t0,t1,0u,1u,kr0,kr1);      // k_ref
    u32 u0,u1;  tf2x32(t0,t1,0u,0u,u0,u1);
    u32 w0,w1;  tf2x32(u0,u1,0u,1u,w0,w1);         // k_state
    u32* p=KST+6*(t-1);
    p[0]=ka0;p[1]=ka1;p[2]=kr0;p[3]=kr1;p[4]=w0;p[5]=w1;
  }
}

// ======================= k_state: r10 VERBATIM (frozen — transcendental bits) ====
__global__ __launch_bounds__(64) void k_state(
    const float* __restrict__ obs, const float* __restrict__ inp,
    const float* __restrict__ mean, const float* __restrict__ icov,
    const float* __restrict__ coeff, const float* __restrict__ ecov,
    const float* __restrict__ refst, const float* __restrict__ Om,
    const float* __restrict__ ph, const float* __restrict__ Cm,
    float* wsf)
{
  const int i=blockIdx.x*64+threadIdx.x;
  const u32* KI=(const u32*)(wsf+WS_KEYINIT);
  const u32* KST=(const u32*)(wsf+WS_KST);
  float* LL=wsf+WS_LL; float* H=wsf+WS_H; float* LLN=wsf+WS_LLN;
  float* CKPT=wsf+WS_CKPT;

  float LEp[36];
  { float L0p[36];
    chol8(icov,L0p); chol8(ecov,LEp);
    float st[8];
    if(i==NS-1){ for(int d=0;d<8;d++) st[d]=refst[d]; }
    else {
      float eps[8];
      for(int d=0;d<8;d++) eps[d]=jax_normal_elem(KI[0],KI[1],(u32)(i*8+d));
      for(int d=0;d<8;d++){ float m=0.0f; for(int k=0;k<=d;k++) m+=eps[k]*L0p[d*(d+1)/2+k]; st[d]=mean[d]+m; }
    }
    { float* ck=CKPT+(size_t)i*8;     // checkpoint row 0 = state at t=0
      for(int d=0;d<8;d++) ck[d]=st[d]; }

    float c_ll=4.0f*logf((float)(2.0*M_PI*0.1*0.1));
    float hc1=0.0f; for(int d=0;d<8;d++) hc1+=logf(LEp[d*(d+1)/2+d]);
    float hc2=4.0f*logf((float)(2.0*M_PI));
    const float SSQ=(float)(0.1*0.1);

    for(int t=1;t<NSTEPS;t++){
      // --- A: exact ---
      float z[12];
      for(int d=0;d<8;d++) z[d]=st[d];
      for(int k=0;k<4;k++) z[8+k]=inp[t*4+k];
      float ax[8]={0,0,0,0,0,0,0,0};
      for(int j=0;j<DBc;j++){
        float dot=0.0f;
        #pragma unroll
        for(int k=0;k<12;k++) dot+=z[k]*Om[j*12+k];
        float b=cosf(dot+ph[j]);
        #pragma unroll
        for(int d=0;d<8;d++) ax[d]+=b*coeff[d*DBc+j];
      }
      float S=0.0f;
      for(int d=0;d<8;d++){
        float m=0.0f;
        #pragma unroll
        for(int k=0;k<8;k++) m+=ax[k]*Cm[d*8+k];
        float r=obs[t*8+d]-m; S+=r*r;
      }
      float ll=(-0.5f*S)/SSQ - c_ll;
      float sol[8]; float q=0.0f;
      for(int d=0;d<8;d++){
        float s=refst[t*8+d]-ax[d];
        for(int k=0;k<d;k++) s-=LEp[d*(d+1)/2+k]*sol[k];
        sol[d]=s/LEp[d*(d+1)/2+d];
        q+=sol[d]*sol[d];
      }
      float h=(-0.5f*q - hc1) - hc2;
      LL[(size_t)t*NS+i]=ll;
      H[(size_t)t*NS+i]=h;

      // --- P: exact ---
      if(i==NS-1){ for(int d=0;d<8;d++) st[d]=refst[t*8+d]; }
      else {
        const u32* kp=KST+6*(t-1);
        float eps[8];
        for(int d=0;d<8;d++) eps[d]=jax_normal_elem(kp[4],kp[5],(u32)(i*8+d));
        for(int d=0;d<8;d++){ float m=0.0f; for(int k=0;k<=d;k++) m+=eps[k]*LEp[d*(d+1)/2+k]; st[d]=ax[d]+m; }
      }
      float S2n=0.0f;
      for(int d=0;d<8;d++){
        float m=0.0f;
        #pragma unroll
        for(int k=0;k<8;k++) m+=st[k]*Cm[d*8+k];
        float r=obs[t*8+d]-m; S2n+=r*r;
      }
      float lln=(-0.5f*S2n)/SSQ - c_ll;
      LLN[(size_t)t*NS+i]=lln;

      if((t&7)==0){
        float* ck=CKPT+((size_t)(t>>3)*NS+i)*8;
        for(int d=0;d<8;d++) ck[d]=st[d];
      }
    }
  }
}

// ======================= k_weights: r12 arithmetic verbatim; search phase now
// exploits tau monotonicity: binary search for k=0, linear advance for k=1..7
// from the previous UNCLAMPED lower_bound. Provably identical indices (same
// monotone CUM array, same first-index-with-CUM>=tau semantics, same clamp).
__global__ __launch_bounds__(1024) void k_weights(float* wsf){
  const int tid=threadIdx.x;
  const int lane=tid&63;
  const int wid=tid>>6;       // 0..15
  const int base=tid*8;
  const u32* KST=(const u32*)(wsf+WS_KST);
  const u32* KF=(const u32*)(wsf+WS_KFIN);
  const float* LL=wsf+WS_LL;
  const float* H=wsf+WS_H;
  const float* LLN=wsf+WS_LLN;
  u16* ANC=(u16*)(wsf+WS_ANC_F);
  int* IDX=(int*)(wsf+WS_IDX);

  __shared__ float CUM[NS];                 // 32 KB
  __shared__ float CUM2[NS];                // 32 KB
  __shared__ float WMX[16],WMX2[16],WSM[16],WSM2[16];

  float lw[8];
  #pragma unroll
  for(int k=0;k<8;k++) lw[k]=0.0f;

  // prefetch rows for t=1
  float r_ll[8],r_h[8],r_lln[8];
  {
    const float* LLt=LL+(size_t)1*NS;
    const float* Ht=H+(size_t)1*NS;
    const float* LLNt=LLN+(size_t)1*NS;
    #pragma unroll
    for(int k=0;k<8;k++){ r_ll[k]=LLt[base+k]; r_h[k]=Ht[base+k]; r_lln[k]=LLNt[base+k]; }
  }

  for(int t=1;t<NSTEPS;t++){
    const u32* kp=KST+6*(t-1);
    const float* LLt=LL+(size_t)t*NS;   // for the LLt[lo] gather

    float s1v[8],s2v[8];
    float m1=-INFINITY,m2=-INFINITY;
    #pragma unroll
    for(int k=0;k<8;k++){
      float llv=r_ll[k], hv=r_h[k];
      s1v[k]=llv+lw[k];
      s2v[k]=s1v[k]+hv;
      m1=fmaxf(m1,s1v[k]); m2=fmaxf(m2,s2v[k]);
    }
    float wm1=wave_max(m1), wm2=wave_max(m2);
    if(lane==0){ WMX[wid]=wm1; WMX2[wid]=wm2; }
    __syncthreads();                               // sync 1
    float M1=WMX[0],M2=WMX2[0];
    #pragma unroll
    for(int w=1;w<16;w++){ M1=fmaxf(M1,WMX[w]); M2=fmaxf(M2,WMX2[w]); }

    float e1[8],e2[8]; float ts1=0.0f,ts2=0.0f;
    #pragma unroll
    for(int k=0;k<8;k++){
      e1[k]=expf(s1v[k]-M1); ts1+=e1[k];
      e2[k]=expf(s2v[k]-M2); ts2+=e2[k];
    }
    float is1=wave_incl_scan(ts1,lane);
    float is2=wave_incl_scan(ts2,lane);
    if(lane==63){ WSM[wid]=is1; WSM2[wid]=is2; }
    __syncthreads();                               // sync 2
    float T1=0.0f,T2=0.0f,woff1=0.0f,woff2=0.0f;
    #pragma unroll
    for(int w=0;w<16;w++){
      float a=WSM[w], b=WSM2[w];
      T1+=a; T2+=b;
      if(w<wid){ woff1+=a; woff2+=b; }
    }
    float excl1=woff1+(is1-ts1);
    float excl2=woff2+(is2-ts2);

    { float run=excl1;
      #pragma unroll
      for(int k=0;k<8;k++){ run+=e1[k]; CUM[base+k]=run; } }
    { float run=excl2;
      #pragma unroll
      for(int k=0;k<8;k++){ run+=e2[k]; CUM2[base+k]=run; } }
    __syncthreads();                               // sync 3

    float lwn[8];
    float u1=jax_uniform01_scalar(kp[0],kp[1]);
    int lo=0;                       // carried UNCLAMPED lower_bound
    #pragma unroll 1
    for(int k=0;k<8;k++){
      int i=base+k;
      if(i!=NS-1){
        float pos=((float)i+u1)*(1.0f/8192.0f);
        float tau=pos*T1;
        if(k==0){
          int l=0,hgh=NS;
          while(l<hgh){ int mid=(l+hgh)>>1; if(CUM[mid]<tau) l=mid+1; else hgh=mid; }
          lo=l;
        } else {
          while(lo<NS && CUM[lo]<tau) lo++;
        }
        int loc=(lo>NS-1)?NS-1:lo;
        ANC[(size_t)(t-1)*NS+i]=(u16)loc;
        lwn[k]=r_lln[k]-LLt[loc];
      }
    }
    if(tid==1023){
      float u2=jax_uniform01_scalar(kp[2],kp[3]);
      float tau=u2*T2;
      int l=0,hgh=NS;
      while(l<hgh){ int mid=(l+hgh)>>1; if(CUM2[mid]<tau) l=mid+1; else hgh=mid; }
      if(l>NS-1) l=NS-1;
      ANC[(size_t)(t-1)*NS+(NS-1)]=(u16)l;
      lwn[7]=r_lln[7]-LLt[l];
    }
    // prefetch next step's rows (hidden under remaining threads' searches)
    if(t+1<NSTEPS){
      const float* LLt2=LL+(size_t)(t+1)*NS;
      const float* Ht2=H+(size_t)(t+1)*NS;
      const float* LLNt2=LLN+(size_t)(t+1)*NS;
      #pragma unroll
      for(int k=0;k<8;k++){ r_ll[k]=LLt2[base+k]; r_h[k]=Ht2[base+k]; r_lln[k]=LLNt2[base+k]; }
    }
    #pragma unroll
    for(int k=0;k<8;k++) lw[k]=lwn[k];
    // no trailing sync: next iteration's sync 1 orders this step's CUM reads
    // before the next CUM writes (which happen only after sync 2).
  }

  // ===== final softmax over lw, draw, backward chain (r12 verbatim) =====
  {
    float m=-INFINITY;
    #pragma unroll
    for(int k=0;k<8;k++) m=fmaxf(m,lw[k]);
    float wm=wave_max(m);
    if(lane==0) WMX[wid]=wm;
    __syncthreads();
    float M=WMX[0];
    #pragma unroll
    for(int w=1;w<16;w++) M=fmaxf(M,WMX[w]);
    float e[8]; float ts=0.0f;
    #pragma unroll
    for(int k=0;k<8;k++){ e[k]=expf(lw[k]-M); ts+=e[k]; }
    float is=wave_incl_scan(ts,lane);
    if(lane==63) WSM[wid]=is;
    __syncthreads();
    float T=0.0f,woff=0.0f;
    #pragma unroll
    for(int w=0;w<16;w++){ T+=WSM[w]; if(w<wid) woff+=WSM[w]; }
    float run=woff+(is-ts);
    #pragma unroll
    for(int k=0;k<8;k++){ run+=e[k]; CUM[base+k]=run; }
    __syncthreads();
    if(tid==0){
      float u=jax_uniform01_scalar(KF[0],KF[1]);
      float tau=u*T;
      int lo=0,hi=NS;
      while(lo<hi){ int mid=(lo+hi)>>1; if(CUM[mid]<tau) lo=mid+1; else hi=mid; }
      if(lo>NS-1) lo=NS-1;
      int b=lo;
      IDX[NSTEPS-1]=b;
      for(int r=NSTEPS-2;r>=0;r--){ b=(int)ANC[(size_t)r*NS+b]; IDX[r]=b; }
    }
  }
}

// ======================= k_replay: r10 VERBATIM (frozen) ================
__global__ __launch_bounds__(256) void k_replay(
    const float* __restrict__ inp, const float* __restrict__ refst,
    const float* __restrict__ ecov, const float* __restrict__ Om,
    const float* __restrict__ ph, const float* __restrict__ coeff,
    const float* __restrict__ wsf, float* __restrict__ out)
{
  int task=blockIdx.x*blockDim.x+threadIdx.x;
  if(task>=NSTEPS) return;
  const int* IDX=(const int*)(wsf+WS_IDX);
  const u32* KST=(const u32*)(wsf+WS_KST);
  const float* CKPT=wsf+WS_CKPT;
  int t=task, p=IDX[t];
  if(p==NS-1){ for(int d=0;d<8;d++) out[t*8+d]=refst[t*8+d]; return; }
  float LEp[36]; chol8(ecov,LEp);
  int c=(t>>3)<<3;
  const float* ck=CKPT+((size_t)(t>>3)*NS+p)*8;
  float st[8];
  for(int d=0;d<8;d++) st[d]=ck[d];
  for(int s=c+1;s<=t;s++){
    float z[12];
    for(int d=0;d<8;d++) z[d]=st[d];
    for(int k=0;k<4;k++) z[8+k]=inp[s*4+k];
    float ax[8]={0,0,0,0,0,0,0,0};
    for(int j=0;j<DBc;j++){
      float dot=0.0f;
      #pragma unroll
      for(int k=0;k<12;k++) dot+=z[k]*Om[j*12+k];
      float b=cosf(dot+ph[j]);
      #pragma unroll
      for(int d=0;d<8;d++) ax[d]+=b*coeff[d*DBc+j];
    }
    const u32* kp=KST+6*(s-1);
    float eps[8];
    for(int d=0;d<8;d++) eps[d]=jax_normal_elem(kp[4],kp[5],(u32)(p*8+d));
    for(int d=0;d<8;d++){ float m=0.0f; for(int k=0;k<=d;k++) m+=eps[k]*LEp[d*(d+1)/2+k]; st[d]=ax[d]+m; }
  }
  for(int d=0;d<8;d++) out[t*8+d]=st[d];
}

// ======================= launch =======================
extern "C" void kernel_launch(void* const* d_in, const int* in_sizes, int n_in,
                              void* d_out, int out_size, void* d_ws, size_t ws_size,
                              hipStream_t stream) {
  const float* obs  =(const float*)d_in[0];
  const float* inp  =(const float*)d_in[1];
  const float* mean =(const float*)d_in[2];
  const float* icov =(const float*)d_in[3];
  const float* coeff=(const float*)d_in[4];
  const float* ecov =(const float*)d_in[5];
  const float* refst=(const float*)d_in[6];
  const float* Om   =(const float*)d_in[7];
  const float* ph   =(const float*)d_in[8];
  const float* Cm   =(const float*)d_in[9];
  const int*   seedp=(const int*)d_in[10];
  float* wsf=(float*)d_ws;
  float* out=(float*)d_out;

  hipLaunchKernelGGL(k_pre, dim3(1), dim3(256), 0, stream, seedp, wsf);
  hipLaunchKernelGGL(k_state, dim3(NS/64), dim3(64), 0, stream,
                     obs, inp, mean, icov, coeff, ecov, refst, Om, ph, Cm, wsf);
  hipLaunchKernelGGL(k_weights, dim3(1), dim3(1024), 0, stream, wsf);
  hipLaunchKernelGGL(k_replay, dim3(1), dim3(256), 0, stream,
                     inp, refst, ecov, Om, ph, coeff, wsf, out);
}

// Round 15
// 11379.470 us; speedup vs baseline: 2.6234x; 2.6234x over previous
//
#include <hip/hip_runtime.h>
#include <stdint.h>
#include <math.h>

#define NS 8192
#define NSTEPS 200
#define DBc 128

typedef unsigned int u32;
typedef unsigned short u16;

// ws float-offset layout (float slots), total ~29.5 MB
#define WS_KEYINIT 64      // u32[2]
#define WS_KFIN   66       // u32[2]
#define WS_KC     128      // u32[400]
#define WS_KST    640      // u32[6*199] -> ends 1834
#define WS_IDX    2048     // int[200]
#define WS_LL     4096                    // [200][8192] -> ends 1642496
#define WS_H      (WS_LL+NSTEPS*NS)       // -> ends 3280896
#define WS_LLN    (WS_H+NSTEPS*NS)        // -> ends 4919296
#define WS_ANC_F  (WS_LLN+NSTEPS*NS)      // u16[199*8192] = 815104 slots -> ends 5734400
#define WS_CKPT   (WS_ANC_F+(NSTEPS-1)*NS/2)  // [25][8192][8] -> ends 7372800

// ======================= threefry2x32-20 (validated r1-r12) =======================
__device__ __forceinline__ u32 rotl32(u32 v, int r){ return (v<<r)|(v>>(32-r)); }

__device__ __forceinline__ void tf2x32(u32 k0,u32 k1,u32 c0,u32 c1,u32&o0,u32&o1){
  u32 ks2 = k0^k1^0x1BD11BDAu;
  u32 x0=c0+k0, x1=c1+k1;
#define TFR(R) { x0+=x1; x1=rotl32(x1,(R)); x1^=x0; }
  TFR(13) TFR(15) TFR(26) TFR(6)
  x0+=k1;  x1+=ks2+1u;
  TFR(17) TFR(29) TFR(16) TFR(24)
  x0+=ks2; x1+=k0+2u;
  TFR(13) TFR(15) TFR(26) TFR(6)
  x0+=k0;  x1+=k1+3u;
  TFR(17) TFR(29) TFR(16) TFR(24)
  x0+=k1;  x1+=ks2+4u;
  TFR(13) TFR(15) TFR(26) TFR(6)
  x0+=ks2; x1+=k0+5u;
#undef TFR
  o0=x0; o1=x1;
}

__device__ __forceinline__ u32 jax_bits_elem(u32 k0,u32 k1,u32 i){
  u32 a,b; tf2x32(k0,k1,0u,i,a,b); return a^b;
}

__device__ __forceinline__ float bits_to_f01(u32 bits){
  return __uint_as_float((bits>>9)|0x3f800000u) - 1.0f;
}

__device__ __forceinline__ float log1pf_acc(float a){
#pragma clang fp contract(off)
  float u = 1.0f + a;
  if (u == 1.0f) return a;
  float l = logf(u);
  return l * (a / (u - 1.0f));
}

__device__ __forceinline__ float erfinv_xla(float x){
#pragma clang fp contract(off)
  float a = -(x*x);
  float w = -log1pf_acc(a);
  float p;
  if (w < 5.0f){
    w = w - 2.5f;
    p = 2.81022636e-08f;
    p = 3.43273939e-07f + p*w;
    p = -3.5233877e-06f + p*w;
    p = -4.39150654e-06f + p*w;
    p = 0.00021858087f  + p*w;
    p = -0.00125372503f + p*w;
    p = -0.00417768164f + p*w;
    p = 0.246640727f    + p*w;
    p = 1.50140941f     + p*w;
  } else {
    w = sqrtf(w) - 3.0f;
    p = -0.000200214257f;
    p = 0.000100950558f + p*w;
    p = 0.00134934322f  + p*w;
    p = -0.00367342844f + p*w;
    p = 0.00573950773f  + p*w;
    p = -0.0076224613f  + p*w;
    p = 0.00943887047f  + p*w;
    p = 1.00167406f     + p*w;
    p = 2.83297682f     + p*w;
  }
  return p*x;
}

__device__ __forceinline__ float jax_normal_elem(u32 k0,u32 k1,u32 i){
#pragma clang fp contract(off)
  float f = bits_to_f01(jax_bits_elem(k0,k1,i));
  float u = f*2.0f + (-0.99999994039535522f);
  u = fmaxf(-0.99999994039535522f, u);
  return 1.41421356237309515f * erfinv_xla(u);
}

__device__ __forceinline__ float jax_uniform01_scalar(u32 k0,u32 k1){
  return bits_to_f01(jax_bits_elem(k0,k1,0u));
}

// ======================= wave helpers =======================
__device__ __forceinline__ float wave_max(float v){
  #pragma unroll
  for(int m=1;m<64;m<<=1) v=fmaxf(v,__shfl_xor(v,m,64));
  return v;
}
__device__ __forceinline__ float wave_incl_scan(float v,int lane){
  #pragma unroll
  for(int o=1;o<64;o<<=1){ float u=__shfl_up(v,o,64); if(lane>=o) v+=u; }
  return v;
}

__device__ void chol8(const float* A,float* L){
  for(int c=0;c<8;c++){
    for(int r=c;r<8;r++){
      float s=A[r*8+c];
      for(int k=0;k<c;k++) s-=L[r*(r+1)/2+k]*L[c*(c+1)/2+k];
      L[r*(r+1)/2+c]=(r==c)? sqrtf(s) : s/L[c*(c+1)/2+c];
    }
  }
}

// ======================= k_pre: key chain (validated r5-r12) =======================
__global__ __launch_bounds__(256) void k_pre(const int* __restrict__ seedp, float* wsf){
  u32* KI=(u32*)(wsf+WS_KEYINIT); u32* KF=(u32*)(wsf+WS_KFIN);
  u32* KC=(u32*)(wsf+WS_KC); u32* KST=(u32*)(wsf+WS_KST);
  int tid=threadIdx.x;
  if(tid==0){
    u32 s=(u32)seedp[0];
    u32 a,b;
    tf2x32(0u,s,0u,0u,a,b); KC[0]=a; KC[1]=b;      // key_0 = split(key).child0
    tf2x32(0u,s,0u,1u,a,b); KI[0]=a; KI[1]=b;      // key_init = child1
    for(int t=1;t<NSTEPS;t++){
      tf2x32(KC[2*(t-1)],KC[2*(t-1)+1],0u,0u,a,b);
      KC[2*t]=a; KC[2*t+1]=b;
    }
    KF[0]=KC[2*(NSTEPS-1)]; KF[1]=KC[2*(NSTEPS-1)+1];
  }
  __syncthreads();
  int t=tid;
  if(t>=1 && t<NSTEPS){
    u32 k0=KC[2*(t-1)], k1=KC[2*(t-1)+1];
    u32 s0,s1; tf2x32(k0,k1,0u,1u,s0,s1);          // key_step
    u32 ka0,ka1; tf2x32(s0,s1,0u,1u,ka0,ka1);      // k_anc
    u32 t0,t1;  tf2x32(s0,s1,0u,0u,t0,t1);
    u32 kr0,kr1; tf2x32(t0,t1,0u,1u,kr0,kr1);      // k_ref
    u32 u0,u1;  tf2x32(t0,t1,0u,0u,u0,u1);
    u32 w0,w1;  tf2x32(u0,u1,0u,1u,w0,w1);         // k_state
    u32* p=KST+6*(t-1);
    p[0]=ka0;p[1]=ka1;p[2]=kr0;p[3]=kr1;p[4]=w0;p[5]=w1;
  }
}

// ======================= k_state: body VERBATIM (r10); geometry 16x512 for
// 2 waves/SIMD latency hiding. Loop text inline at kernel top level (the
// validated-safe envelope: r2/r3/r5/r6/r9/r10 contexts all preserved bits).
__global__ __launch_bounds__(512) void k_state(
    const float* __restrict__ obs, const float* __restrict__ inp,
    const float* __restrict__ mean, const float* __restrict__ icov,
    const float* __restrict__ coeff, const float* __restrict__ ecov,
    const float* __restrict__ refst, const float* __restrict__ Om,
    const float* __restrict__ ph, const float* __restrict__ Cm,
    float* wsf)
{
  const int i=blockIdx.x*512+threadIdx.x;
  const u32* KI=(const u32*)(wsf+WS_KEYINIT);
  const u32* KST=(const u32*)(wsf+WS_KST);
  float* LL=wsf+WS_LL; float* H=wsf+WS_H; float* LLN=wsf+WS_LLN;
  float* CKPT=wsf+WS_CKPT;

  float LEp[36];
  { float L0p[36];
    chol8(icov,L0p); chol8(ecov,LEp);
    float st[8];
    if(i==NS-1){ for(int d=0;d<8;d++) st[d]=refst[d]; }
    else {
      float eps[8];
      for(int d=0;d<8;d++) eps[d]=jax_normal_elem(KI[0],KI[1],(u32)(i*8+d));
      for(int d=0;d<8;d++){ float m=0.0f; for(int k=0;k<=d;k++) m+=eps[k]*L0p[d*(d+1)/2+k]; st[d]=mean[d]+m; }
    }
    { float* ck=CKPT+(size_t)i*8;     // checkpoint row 0 = state at t=0
      for(int d=0;d<8;d++) ck[d]=st[d]; }

    float c_ll=4.0f*logf((float)(2.0*M_PI*0.1*0.1));
    float hc1=0.0f; for(int d=0;d<8;d++) hc1+=logf(LEp[d*(d+1)/2+d]);
    float hc2=4.0f*logf((float)(2.0*M_PI));
    const float SSQ=(float)(0.1*0.1);

    for(int t=1;t<NSTEPS;t++){
      // --- A: exact ---
      float z[12];
      for(int d=0;d<8;d++) z[d]=st[d];
      for(int k=0;k<4;k++) z[8+k]=inp[t*4+k];
      float ax[8]={0,0,0,0,0,0,0,0};
      for(int j=0;j<DBc;j++){
        float dot=0.0f;
        #pragma unroll
        for(int k=0;k<12;k++) dot+=z[k]*Om[j*12+k];
        float b=cosf(dot+ph[j]);
        #pragma unroll
        for(int d=0;d<8;d++) ax[d]+=b*coeff[d*DBc+j];
      }
      float S=0.0f;
      for(int d=0;d<8;d++){
        float m=0.0f;
        #pragma unroll
        for(int k=0;k<8;k++) m+=ax[k]*Cm[d*8+k];
        float r=obs[t*8+d]-m; S+=r*r;
      }
      float ll=(-0.5f*S)/SSQ - c_ll;
      float sol[8]; float q=0.0f;
      for(int d=0;d<8;d++){
        float s=refst[t*8+d]-ax[d];
        for(int k=0;k<d;k++) s-=LEp[d*(d+1)/2+k]*sol[k];
        sol[d]=s/LEp[d*(d+1)/2+d];
        q+=sol[d]*sol[d];
      }
      float h=(-0.5f*q - hc1) - hc2;
      LL[(size_t)t*NS+i]=ll;
      H[(size_t)t*NS+i]=h;

      // --- P: exact ---
      if(i==NS-1){ for(int d=0;d<8;d++) st[d]=refst[t*8+d]; }
      else {
        const u32* kp=KST+6*(t-1);
        float eps[8];
        for(int d=0;d<8;d++) eps[d]=jax_normal_elem(kp[4],kp[5],(u32)(i*8+d));
        for(int d=0;d<8;d++){ float m=0.0f; for(int k=0;k<=d;k++) m+=eps[k]*LEp[d*(d+1)/2+k]; st[d]=ax[d]+m; }
      }
      float S2n=0.0f;
      for(int d=0;d<8;d++){
        float m=0.0f;
        #pragma unroll
        for(int k=0;k<8;k++) m+=st[k]*Cm[d*8+k];
        float r=obs[t*8+d]-m; S2n+=r*r;
      }
      float lln=(-0.5f*S2n)/SSQ - c_ll;
      LLN[(size_t)t*NS+i]=lln;

      if((t&7)==0){
        float* ck=CKPT+((size_t)(t>>3)*NS+i)*8;
        for(int d=0;d<8;d++) ck[d]=st[d];
      }
    }
  }
}

// ======================= k_weights: r12 VERBATIM (passing, 2.85 ms) ====
__global__ __launch_bounds__(1024) void k_weights(float* wsf){
  const int tid=threadIdx.x;
  const int lane=tid&63;
  const int wid=tid>>6;       // 0..15
  const int base=tid*8;
  const u32* KST=(const u32*)(wsf+WS_KST);
  const u32* KF=(const u32*)(wsf+WS_KFIN);
  const float* LL=wsf+WS_LL;
  const float* H=wsf+WS_H;
  const float* LLN=wsf+WS_LLN;
  u16* ANC=(u16*)(wsf+WS_ANC_F);
  int* IDX=(int*)(wsf+WS_IDX);

  __shared__ float CUM[NS];                 // 32 KB
  __shared__ float CUM2[NS];                // 32 KB
  __shared__ float WMX[16],WMX2[16],WSM[16],WSM2[16];

  float lw[8];
  #pragma unroll
  for(int k=0;k<8;k++) lw[k]=0.0f;

  // prefetch rows for t=1
  float r_ll[8],r_h[8],r_lln[8];
  {
    const float* LLt=LL+(size_t)1*NS;
    const float* Ht=H+(size_t)1*NS;
    const float* LLNt=LLN+(size_t)1*NS;
    #pragma unroll
    for(int k=0;k<8;k++){ r_ll[k]=LLt[base+k]; r_h[k]=Ht[base+k]; r_lln[k]=LLNt[base+k]; }
  }

  for(int t=1;t<NSTEPS;t++){
    const u32* kp=KST+6*(t-1);
    const float* LLt=LL+(size_t)t*NS;   // for the LLt[lo] gather

    float s1v[8],s2v[8];
    float m1=-INFINITY,m2=-INFINITY;
    #pragma unroll
    for(int k=0;k<8;k++){
      float llv=r_ll[k], hv=r_h[k];
      s1v[k]=llv+lw[k];
      s2v[k]=s1v[k]+hv;
      m1=fmaxf(m1,s1v[k]); m2=fmaxf(m2,s2v[k]);
    }
    float wm1=wave_max(m1), wm2=wave_max(m2);
    if(lane==0){ WMX[wid]=wm1; WMX2[wid]=wm2; }
    __syncthreads();                               // sync 1
    float M1=WMX[0],M2=WMX2[0];
    #pragma unroll
    for(int w=1;w<16;w++){ M1=fmaxf(M1,WMX[w]); M2=fmaxf(M2,WMX2[w]); }

    float e1[8],e2[8]; float ts1=0.0f,ts2=0.0f;
    #pragma unroll
    for(int k=0;k<8;k++){
      e1[k]=expf(s1v[k]-M1); ts1+=e1[k];
      e2[k]=expf(s2v[k]-M2); ts2+=e2[k];
    }
    float is1=wave_incl_scan(ts1,lane);
    float is2=wave_incl_scan(ts2,lane);
    if(lane==63){ WSM[wid]=is1; WSM2[wid]=is2; }
    __syncthreads();                               // sync 2
    float T1=0.0f,T2=0.0f,woff1=0.0f,woff2=0.0f;
    #pragma unroll
    for(int w=0;w<16;w++){
      float a=WSM[w], b=WSM2[w];
      T1+=a; T2+=b;
      if(w<wid){ woff1+=a; woff2+=b; }
    }
    float excl1=woff1+(is1-ts1);
    float excl2=woff2+(is2-ts2);

    { float run=excl1;
      #pragma unroll
      for(int k=0;k<8;k++){ run+=e1[k]; CUM[base+k]=run; } }
    { float run=excl2;
      #pragma unroll
      for(int k=0;k<8;k++){ run+=e2[k]; CUM2[base+k]=run; } }
    __syncthreads();                               // sync 3

    float lwn[8];
    float u1=jax_uniform01_scalar(kp[0],kp[1]);
    #pragma unroll
    for(int k=0;k<8;k++){
      int i=base+k;
      if(i!=NS-1){
        float pos=((float)i+u1)*(1.0f/8192.0f);
        float tau=pos*T1;
        int lo=0,hi=NS;
        while(lo<hi){ int mid=(lo+hi)>>1; if(CUM[mid]<tau) lo=mid+1; else hi=mid; }
        if(lo>NS-1) lo=NS-1;
        ANC[(size_t)(t-1)*NS+i]=(u16)lo;
        lwn[k]=r_lln[k]-LLt[lo];
      }
    }
    if(tid==1023){
      float u2=jax_uniform01_scalar(kp[2],kp[3]);
      float tau=u2*T2;
      int lo=0,hi=NS;
      while(lo<hi){ int mid=(lo+hi)>>1; if(CUM2[mid]<tau) lo=mid+1; else hi=mid; }
      if(lo>NS-1) lo=NS-1;
      ANC[(size_t)(t-1)*NS+(NS-1)]=(u16)lo;
      lwn[7]=r_lln[7]-LLt[lo];
    }
    // prefetch next step's rows (hidden under remaining threads' searches)
    if(t+1<NSTEPS){
      const float* LLt2=LL+(size_t)(t+1)*NS;
      const float* Ht2=H+(size_t)(t+1)*NS;
      const float* LLNt2=LLN+(size_t)(t+1)*NS;
      #pragma unroll
      for(int k=0;k<8;k++){ r_ll[k]=LLt2[base+k]; r_h[k]=Ht2[base+k]; r_lln[k]=LLNt2[base+k]; }
    }
    #pragma unroll
    for(int k=0;k<8;k++) lw[k]=lwn[k];
    // no trailing sync: next iteration's sync 1 orders this step's CUM reads
    // before the next CUM writes (which happen only after sync 2).
  }

  // ===== final softmax over lw, draw, backward chain (r12 verbatim) =====
  {
    float m=-INFINITY;
    #pragma unroll
    for(int k=0;k<8;k++) m=fmaxf(m,lw[k]);
    float wm=wave_max(m);
    if(lane==0) WMX[wid]=wm;
    __syncthreads();
    float M=WMX[0];
    #pragma unroll
    for(int w=1;w<16;w++) M=fmaxf(M,WMX[w]);
    float e[8]; float ts=0.0f;
    #pragma unroll
    for(int k=0;k<8;k++){ e[k]=expf(lw[k]-M); ts+=e[k]; }
    float is=wave_incl_scan(ts,lane);
    if(lane==63) WSM[wid]=is;
    __syncthreads();
    float T=0.0f,woff=0.0f;
    #pragma unroll
    for(int w=0;w<16;w++){ T+=WSM[w]; if(w<wid) woff+=WSM[w]; }
    float run=woff+(is-ts);
    #pragma unroll
    for(int k=0;k<8;k++){ run+=e[k]; CUM[base+k]=run; }
    __syncthreads();
    if(tid==0){
      float u=jax_uniform01_scalar(KF[0],KF[1]);
      float tau=u*T;
      int lo=0,hi=NS;
      while(lo<hi){ int mid=(lo+hi)>>1; if(CUM[mid]<tau) lo=mid+1; else hi=mid; }
      if(lo>NS-1) lo=NS-1;
      int b=lo;
      IDX[NSTEPS-1]=b;
      for(int r=NSTEPS-2;r>=0;r--){ b=(int)ANC[(size_t)r*NS+b]; IDX[r]=b; }
    }
  }
}

// ======================= k_replay: r10 VERBATIM (frozen) ================
__global__ __launch_bounds__(256) void k_replay(
    const float* __restrict__ inp, const float* __restrict__ refst,
    const float* __restrict__ ecov, const float* __restrict__ Om,
    const float* __restrict__ ph, const float* __restrict__ coeff,
    const float* __restrict__ wsf, float* __restrict__ out)
{
  int task=blockIdx.x*blockDim.x+threadIdx.x;
  if(task>=NSTEPS) return;
  const int* IDX=(const int*)(wsf+WS_IDX);
  const u32* KST=(const u32*)(wsf+WS_KST);
  const float* CKPT=wsf+WS_CKPT;
  int t=task, p=IDX[t];
  if(p==NS-1){ for(int d=0;d<8;d++) out[t*8+d]=refst[t*8+d]; return; }
  float LEp[36]; chol8(ecov,LEp);
  int c=(t>>3)<<3;
  const float* ck=CKPT+((size_t)(t>>3)*NS+p)*8;
  float st[8];
  for(int d=0;d<8;d++) st[d]=ck[d];
  for(int s=c+1;s<=t;s++){
    float z[12];
    for(int d=0;d<8;d++) z[d]=st[d];
    for(int k=0;k<4;k++) z[8+k]=inp[s*4+k];
    float ax[8]={0,0,0,0,0,0,0,0};
    for(int j=0;j<DBc;j++){
      float dot=0.0f;
      #pragma unroll
      for(int k=0;k<12;k++) dot+=z[k]*Om[j*12+k];
      float b=cosf(dot+ph[j]);
      #pragma unroll
      for(int d=0;d<8;d++) ax[d]+=b*coeff[d*DBc+j];
    }
    const u32* kp=KST+6*(s-1);
    float eps[8];
    for(int d=0;d<8;d++) eps[d]=jax_normal_elem(kp[4],kp[5],(u32)(p*8+d));
    for(int d=0;d<8;d++){ float m=0.0f; for(int k=0;k<=d;k++) m+=eps[k]*LEp[d*(d+1)/2+k]; st[d]=ax[d]+m; }
  }
  for(int d=0;d<8;d++) out[t*8+d]=st[d];
}

// ======================= launch =======================
extern "C" void kernel_launch(void* const* d_in, const int* in_sizes, int n_in,
                              void* d_out, int out_size, void* d_ws, size_t ws_size,
                              hipStream_t stream) {
  const float* obs  =(const float*)d_in[0];
  const float* inp  =(const float*)d_in[1];
  const float* mean =(const float*)d_in[2];
  const float* icov =(const float*)d_in[3];
  const float* coeff=(const float*)d_in[4];
  const float* ecov =(const float*)d_in[5];
  const float* refst=(const float*)d_in[6];
  const float* Om   =(const float*)d_in[7];
  const float* ph   =(const float*)d_in[8];
  const float* Cm   =(const float*)d_in[9];
  const int*   seedp=(const int*)d_in[10];
  float* wsf=(float*)d_ws;
  float* out=(float*)d_out;

  hipLaunchKernelGGL(k_pre, dim3(1), dim3(256), 0, stream, seedp, wsf);
  hipLaunchKernelGGL(k_state, dim3(NS/512), dim3(512), 0, stream,
                     obs, inp, mean, icov, coeff, ecov, refst, Om, ph, Cm, wsf);
  hipLaunchKernelGGL(k_weights, dim3(1), dim3(1024), 0, stream, wsf);
  hipLaunchKernelGGL(k_replay, dim3(1), dim3(256), 0, stream,
                     inp, refst, ecov, Om, ph, coeff, wsf, out);
}